// Round 1
// baseline (697.891 us; speedup 1.0000x reference)
//
#include <hip/hip_runtime.h>
#include <stdint.h>

#define B_    8
#define CCH   64
#define HW_   4096
#define C512  512

typedef __attribute__((ext_vector_type(8))) short short8v;
typedef __attribute__((ext_vector_type(4))) float f32x4;

__device__ __constant__ int PERM[8][8] = {
  {0,1,2,3,4,5,6,7},
  {3,0,1,2,5,6,7,4},
  {2,3,0,1,6,7,4,5},
  {1,2,3,0,7,4,5,6},
  {4,5,6,7,0,1,2,3},
  {5,6,7,4,3,0,1,2},
  {6,7,4,5,2,3,0,1},
  {7,4,5,6,1,2,3,0},
};

__device__ inline float bf2f(unsigned int u){
  union { unsigned int i; float f; } v; v.i = u << 16; return v.f;
}
__device__ inline unsigned short f2bf(float f){
  union { float f; unsigned int i; } v; v.f = f;
  return (unsigned short)((v.i + 0x7FFFu + ((v.i >> 16) & 1u)) >> 16);
}
__device__ inline unsigned int scale2(unsigned int packed, float a0, float a1, float f){
  float v0 = bf2f(packed & 0xffffu) * a0 * f;
  float v1 = bf2f(packed >> 16)     * a1 * f;
  return (unsigned int)f2bf(v0) | (((unsigned int)f2bf(v1)) << 16);
}
__device__ inline float sigmoidf_(float x){ return 1.f / (1.f + __expf(-x)); }

// ---------------- K2: BN + ReLU + transpose to channel-last bf16, fused channel stats ----
// x: [b][c512][4096] f32  ->  yT: [b][4096][c512] bf16 ; csum/cmax per (b,c512)
__global__ void k_bnrelu_tr(const float* __restrict__ x,
                            const float* __restrict__ gamma, const float* __restrict__ beta,
                            const float* __restrict__ mean,  const float* __restrict__ var,
                            unsigned short* __restrict__ yT,
                            float* __restrict__ csum, unsigned int* __restrict__ cmax){
  __shared__ float lds[64 * 66];
  int bid = blockIdx.x;
  int b  = bid >> 9;
  int r  = bid & 511;
  int ct = r >> 6, pt = r & 63;
  int c0 = ct * 64, p0 = pt * 64;
  int t  = threadIdx.x;
  int cc = t >> 2, q = t & 3;
  int c512 = c0 + cc;
  int ch = c512 >> 3;
  float inv = gamma[ch] * rsqrtf(var[ch] + 2e-5f);
  float sh  = beta[ch] - mean[ch] * inv;
  const float* src = x + ((size_t)(b * C512 + c512)) * HW_ + p0;
  float s_ = 0.f, m_ = 0.f;
#pragma unroll
  for (int i = 0; i < 4; ++i){
    float4 v = *(const float4*)(src + i * 16 + q * 4);
    float a0 = fmaxf(v.x * inv + sh, 0.f);
    float a1 = fmaxf(v.y * inv + sh, 0.f);
    float a2 = fmaxf(v.z * inv + sh, 0.f);
    float a3 = fmaxf(v.w * inv + sh, 0.f);
    int pp = i * 16 + q * 4;
    lds[(pp + 0) * 66 + cc] = a0;
    lds[(pp + 1) * 66 + cc] = a1;
    lds[(pp + 2) * 66 + cc] = a2;
    lds[(pp + 3) * 66 + cc] = a3;
    s_ += (a0 + a1) + (a2 + a3);
    m_ = fmaxf(m_, fmaxf(fmaxf(a0, a1), fmaxf(a2, a3)));
  }
  s_ += __shfl_down(s_, 2); s_ += __shfl_down(s_, 1);
  m_ = fmaxf(m_, __shfl_down(m_, 2)); m_ = fmaxf(m_, __shfl_down(m_, 1));
  if (q == 0){
    atomicAdd(&csum[b * C512 + c512], s_);
    atomicMax(&cmax[b * C512 + c512], __float_as_uint(m_));
  }
  __syncthreads();
  int cc2 = t & 63, ppq = t >> 6;
  unsigned short* dst = yT + ((size_t)(b * HW_ + p0)) * C512 + c0 + cc2;
#pragma unroll
  for (int i = 0; i < 16; ++i){
    int pp = ppq * 16 + i;
    dst[(size_t)pp * C512] = f2bf(lds[pp * 66 + cc2]);
  }
}

// ---------------- K3: channel-attention MLP -> ac[b][g][512] ----------------
__global__ void k_cmlp(const float* __restrict__ csum, const unsigned int* __restrict__ cmax,
                       const float* __restrict__ w1, const float* __restrict__ w2,
                       float* __restrict__ ac){
  __shared__ float vA[512], vM[512];
  __shared__ float wred[4][4];
  __shared__ float rr[2];
  int b = blockIdx.x >> 3, g = blockIdx.x & 7;
  int t = threadIdx.x;
  for (int j = t; j < 512; j += 256){
    int c = j >> 3, h = j & 7;
    int srcj = (c << 3) + PERM[g][h];
    vA[j] = csum[b * 512 + srcj] * (1.f / 4096.f);
    vM[j] = __uint_as_float(cmax[b * 512 + srcj]);
  }
  __syncthreads();
  float pa0 = 0, pa1 = 0, pm0 = 0, pm1 = 0;
  for (int j = t; j < 512; j += 256){
    float wa = w1[j], wb = w1[512 + j];
    pa0 += vA[j] * wa; pa1 += vA[j] * wb;
    pm0 += vM[j] * wa; pm1 += vM[j] * wb;
  }
#pragma unroll
  for (int off = 32; off >= 1; off >>= 1){
    pa0 += __shfl_down(pa0, off); pa1 += __shfl_down(pa1, off);
    pm0 += __shfl_down(pm0, off); pm1 += __shfl_down(pm1, off);
  }
  int wv = t >> 6, ln = t & 63;
  if (ln == 0){ wred[wv][0] = pa0; wred[wv][1] = pa1; wred[wv][2] = pm0; wred[wv][3] = pm1; }
  __syncthreads();
  if (t == 0){
    float hA0 = wred[0][0] + wred[1][0] + wred[2][0] + wred[3][0];
    float hA1 = wred[0][1] + wred[1][1] + wred[2][1] + wred[3][1];
    float hM0 = wred[0][2] + wred[1][2] + wred[2][2] + wred[3][2];
    float hM1 = wred[0][3] + wred[1][3] + wred[2][3] + wred[3][3];
    rr[0] = fmaxf(hA0, 0.f) + fmaxf(hM0, 0.f);
    rr[1] = fmaxf(hA1, 0.f) + fmaxf(hM1, 0.f);
  }
  __syncthreads();
  float r0 = rr[0], r1 = rr[1];
  for (int j = t; j < 512; j += 256){
    float z = r0 * w2[j * 2] + r1 * w2[j * 2 + 1];
    ac[(size_t)(b * 8 + g) * 512 + j] = sigmoidf_(z);
  }
}

// ---------------- K4: spatial stats: mean/max over ci per (b,s,pixel) -> f2[b][16][4096] ---
__global__ void k_sstats(const unsigned short* __restrict__ yT, float* __restrict__ f2){
  int wv = threadIdx.x >> 6, ln = threadIdx.x & 63;
  for (int i = 0; i < 16; ++i){
    int bp = (blockIdx.x * 4 + wv) * 16 + i;  // 0..32767 == b*4096+p
    int b = bp >> 12, p = bp & 4095;
    uint4 u = *(const uint4*)(yT + ((size_t)bp) * 512 + ln * 8);
    float s[8], m[8];
    s[0] = bf2f(u.x & 0xffff); s[1] = bf2f(u.x >> 16);
    s[2] = bf2f(u.y & 0xffff); s[3] = bf2f(u.y >> 16);
    s[4] = bf2f(u.z & 0xffff); s[5] = bf2f(u.z >> 16);
    s[6] = bf2f(u.w & 0xffff); s[7] = bf2f(u.w >> 16);
#pragma unroll
    for (int k = 0; k < 8; ++k) m[k] = s[k];
#pragma unroll
    for (int off = 32; off >= 1; off >>= 1){
#pragma unroll
      for (int k = 0; k < 8; ++k){
        s[k] += __shfl_xor(s[k], off);
        m[k] = fmaxf(m[k], __shfl_xor(m[k], off));
      }
    }
    if (ln == 0){
#pragma unroll
      for (int k = 0; k < 8; ++k){
        f2[((size_t)(b * 2 + 0) * 8 + k) * 4096 + p] = s[k] * (1.f / 64.f);
        f2[((size_t)(b * 2 + 1) * 8 + k) * 4096 + p] = m[k];
      }
    }
  }
}

// ---------------- K5: p4m-transform spatial-attention weights -> wsp[g][16][7][7] ----------
__global__ void k_saw(const float* __restrict__ saw, float* __restrict__ wsp){
  int e = blockIdx.x * 256 + threadIdx.x;
  if (e >= 8 * 16 * 49) return;
  int g = e / 784; int r = e % 784;
  int tch = r / 49; int r2 = r % 49;
  int ky = r2 / 7, kx = r2 % 7;
  int m = tch >> 3, s = tch & 7;
  int a = g >> 2, bb = g & 3;
  int sy, sx;
  if      (bb == 0){ sy = ky;     sx = kx;     }
  else if (bb == 1){ sy = kx;     sx = 6 - ky; }
  else if (bb == 2){ sy = 6 - ky; sx = 6 - kx; }
  else             { sy = 6 - kx; sx = ky;     }
  if (a) sx = 6 - sx;
  int ps = PERM[g][s];
  wsp[e] = saw[((m * 8 + ps) * 7 + sy) * 7 + sx];
}

// ---------------- K6: spatial attention 7x7 conv -> sp[b][g][4096] ------------------------
__global__ void k_sconv(const float* __restrict__ f2, const float* __restrict__ wsp,
                        float* __restrict__ sp){
  __shared__ float wl[8 * 784];
  for (int i = threadIdx.x; i < 6272; i += 256) wl[i] = wsp[i];
  __syncthreads();
  int t = blockIdx.x * 256 + threadIdx.x;  // 0..32767
  int b = t >> 12, p = t & 4095;
  int h = p >> 6, w = p & 63;
  float acc[8] = {0,0,0,0,0,0,0,0};
  for (int tc = 0; tc < 16; ++tc){
    const float* fb = f2 + ((size_t)(b * 16 + tc)) * 4096;
    for (int ky = 0; ky < 7; ++ky){
      int yy = h + ky - 3; if ((unsigned)yy >= 64u) continue;
      for (int kx = 0; kx < 7; ++kx){
        int xx = w + kx - 3; if ((unsigned)xx >= 64u) continue;
        float v = fb[yy * 64 + xx];
        int wi = tc * 49 + ky * 7 + kx;
#pragma unroll
        for (int g = 0; g < 8; ++g) acc[g] += v * wl[g * 784 + wi];
      }
    }
  }
#pragma unroll
  for (int g = 0; g < 8; ++g)
    sp[((size_t)(b * 8 + g)) * 4096 + p] = sigmoidf_(acc[g]);
}

// ---------------- K7: p4m-transform main conv weights -> wt[g][co][tap][c512] bf16 --------
__global__ void k_cw(const float* __restrict__ w, unsigned short* __restrict__ wt){
  int e = blockIdx.x * 256 + threadIdx.x;
  if (e >= 8 * 64 * 9 * 512) return;
  int c = e & 511; int r = e >> 9;
  int tap = r % 9; int r2 = r / 9;
  int co = r2 & 63; int g = r2 >> 6;
  int ci = c >> 3, s = c & 7;
  int ty = tap / 3, tx = tap % 3;
  int a = g >> 2, bb = g & 3;
  int sy, sx;
  if      (bb == 0){ sy = ty;     sx = tx;     }
  else if (bb == 1){ sy = tx;     sx = 2 - ty; }
  else if (bb == 2){ sy = 2 - ty; sx = 2 - tx; }
  else             { sy = 2 - tx; sx = ty;     }
  if (a) sx = 2 - sx;
  int ps = PERM[g][s];
  wt[e] = f2bf(w[((size_t)(co * 64 + ci) * 8 + ps) * 9 + sy * 3 + sx]);
}

// ---------------- K8: main group conv (implicit GEMM, 16x16x32 bf16 MFMA) -----------------
// block = (b, g, 4-row tile). M=64(co) x N=256(pixels) x K=4608 (16 chunks of 32ch x 9 taps)
template<int RES>
__global__ __launch_bounds__(256, 2)
void k_conv(const unsigned short* __restrict__ yT, const unsigned short* __restrict__ wt,
            const float* __restrict__ ac, const float* __restrict__ sp,
            const float* __restrict__ resid, float* __restrict__ out){
  __shared__ __align__(16) unsigned short xl[396 * 40];  // halo pixels x (32ch + 8 pad)
  __shared__ __align__(16) unsigned short wl[320 * 40];  // 5 taps x 64 co rows
  __shared__ float acs[512];
  __shared__ float sps[396];
  int bid = blockIdx.x;
  int b = bid >> 7, g = (bid >> 4) & 7, tile = bid & 15;
  int r0 = tile * 4;
  int t = threadIdx.x;
  int wv = t >> 6, ln = t & 63;
  int lrow = ln & 15, lk = (ln >> 4) * 8;

  for (int j = t; j < 512; j += 256) acs[j] = ac[(size_t)(b * 8 + g) * 512 + j];
  for (int hp = t; hp < 396; hp += 256){
    int hr = hp / 66, hc = hp % 66;
    int gh = r0 + hr - 1, gw = hc - 1;
    float v = 0.f;
    if ((unsigned)gh < 64u && (unsigned)gw < 64u)
      v = sp[((size_t)(b * 8 + g)) * 4096 + gh * 64 + gw];
    sps[hp] = v;
  }
  f32x4 acc[4][4];
#pragma unroll
  for (int mi = 0; mi < 4; ++mi)
#pragma unroll
    for (int ni = 0; ni < 4; ++ni)
      acc[mi][ni] = (f32x4){0.f, 0.f, 0.f, 0.f};
  __syncthreads();

  const unsigned short* ybase = yT + ((size_t)b * HW_) * C512;
  const unsigned short* wbase = wt + ((size_t)g * 64) * 9 * 512;

  for (int kc = 0; kc < 16; ++kc){
    int cb = kc * 32;
    // ---- stage X halo (scaled by ac & sp, zero-padded) ----
    for (int it = 0; it < 7; ++it){
      int task = t + it * 256;
      if (task < 1584){
        int cg = task / 396; int hp = task - cg * 396;
        int hr = hp / 66, hc = hp - hr * 66;
        int gh = r0 + hr - 1, gw = hc - 1;
        uint4 u = {0u, 0u, 0u, 0u};
        if ((unsigned)gh < 64u && (unsigned)gw < 64u)
          u = *(const uint4*)(ybase + ((size_t)(gh * 64 + gw)) * C512 + cb + cg * 8);
        float f = sps[hp];
        const float* a8 = &acs[cb + cg * 8];
        uint4 o;
        o.x = scale2(u.x, a8[0], a8[1], f);
        o.y = scale2(u.y, a8[2], a8[3], f);
        o.z = scale2(u.z, a8[4], a8[5], f);
        o.w = scale2(u.w, a8[6], a8[7], f);
        *(uint4*)&xl[hp * 40 + cg * 8] = o;
      }
    }
    // ---- stage W taps 0..4 ----
    for (int it = 0; it < 5; ++it){
      int task = t + it * 256;
      int cg = task & 3, row = task >> 2;       // row < 320
      int tap = row >> 6, co = row & 63;
      uint4 u = *(const uint4*)(wbase + ((size_t)(co * 9 + tap)) * 512 + cb + cg * 8);
      *(uint4*)&wl[row * 40 + cg * 8] = u;
    }
    __syncthreads();
#pragma unroll
    for (int tap = 0; tap < 5; ++tap){
      const int ty = tap / 3, tx = tap % 3;
      short8v a[4], bf[4];
#pragma unroll
      for (int mi = 0; mi < 4; ++mi)
        a[mi] = *(const short8v*)&wl[(tap * 64 + mi * 16 + lrow) * 40 + lk];
#pragma unroll
      for (int ni = 0; ni < 4; ++ni){
        int n = wv * 64 + ni * 16 + lrow;
        int rr_ = n >> 6, ww = n & 63;
        int hp = (rr_ + ty) * 66 + ww + tx;
        bf[ni] = *(const short8v*)&xl[hp * 40 + lk];
      }
#pragma unroll
      for (int mi = 0; mi < 4; ++mi)
#pragma unroll
        for (int ni = 0; ni < 4; ++ni)
          acc[mi][ni] = __builtin_amdgcn_mfma_f32_16x16x32_bf16(a[mi], bf[ni], acc[mi][ni], 0, 0, 0);
    }
    __syncthreads();
    // ---- stage W taps 5..8 ----
    for (int it = 0; it < 4; ++it){
      int task = t + it * 256;
      int cg = task & 3, row = task >> 2;       // row < 256
      int tapL = row >> 6, co = row & 63;
      uint4 u = *(const uint4*)(wbase + ((size_t)(co * 9 + 5 + tapL)) * 512 + cb + cg * 8);
      *(uint4*)&wl[row * 40 + cg * 8] = u;
    }
    __syncthreads();
#pragma unroll
    for (int tapL = 0; tapL < 4; ++tapL){
      const int tap = 5 + tapL;
      const int ty = tap / 3, tx = tap % 3;
      short8v a[4], bf[4];
#pragma unroll
      for (int mi = 0; mi < 4; ++mi)
        a[mi] = *(const short8v*)&wl[(tapL * 64 + mi * 16 + lrow) * 40 + lk];
#pragma unroll
      for (int ni = 0; ni < 4; ++ni){
        int n = wv * 64 + ni * 16 + lrow;
        int rr_ = n >> 6, ww = n & 63;
        int hp = (rr_ + ty) * 66 + ww + tx;
        bf[ni] = *(const short8v*)&xl[hp * 40 + lk];
      }
#pragma unroll
      for (int mi = 0; mi < 4; ++mi)
#pragma unroll
        for (int ni = 0; ni < 4; ++ni)
          acc[mi][ni] = __builtin_amdgcn_mfma_f32_16x16x32_bf16(a[mi], bf[ni], acc[mi][ni], 0, 0, 0);
    }
    __syncthreads();
  }

  // ---- epilogue: C[co, pixel] -> out[b][co][g][h][w] (+ residual for layer 2) ----
#pragma unroll
  for (int mi = 0; mi < 4; ++mi){
#pragma unroll
    for (int ni = 0; ni < 4; ++ni){
      int n = wv * 64 + ni * 16 + lrow;
      int rr_ = n >> 6, ww = n & 63;
      int gh = r0 + rr_;
#pragma unroll
      for (int q = 0; q < 4; ++q){
        int co = mi * 16 + (ln >> 4) * 4 + q;
        size_t oidx = ((size_t)(b * 64 + co) * 8 + g) * 4096 + gh * 64 + ww;
        float v = acc[mi][ni][q];
        if (RES) v += resid[oidx];
        out[oidx] = v;
      }
    }
  }
}

// =========================================================================================
extern "C" void kernel_launch(void* const* d_in, const int* in_sizes, int n_in,
                              void* d_out, int out_size, void* d_ws, size_t ws_size,
                              hipStream_t stream){
  // workspace layout (bytes)
  const size_t off_yT  = 0;                          // 33,554,432
  const size_t off_wt  = off_yT  + 33554432;         //  4,718,592
  const size_t off_f2  = off_wt  + 4718592;          //  2,097,152
  const size_t off_sp  = off_f2  + 2097152;          //  1,048,576
  const size_t off_cs  = off_sp  + 1048576;          //     16,384
  const size_t off_cm  = off_cs  + 16384;            //     16,384
  const size_t off_ac  = off_cm  + 16384;            //  1,048,576
  const size_t off_wsp = off_ac  + 1048576;          //     25,088
  const size_t total   = off_wsp + 25088;
  if (ws_size < total) return;

  char* ws = (char*)d_ws;
  unsigned short* yT  = (unsigned short*)(ws + off_yT);
  unsigned short* wtb = (unsigned short*)(ws + off_wt);
  float* f2   = (float*)(ws + off_f2);
  float* spb  = (float*)(ws + off_sp);
  float* csum = (float*)(ws + off_cs);
  unsigned int* cmax = (unsigned int*)(ws + off_cm);
  float* acb  = (float*)(ws + off_ac);
  float* wsp  = (float*)(ws + off_wsp);

  const float* x  = (const float*)d_in[0];
  float* h1 = (float*)d_out;   // layer-1 output lives in d_out until overwritten by layer 2

  const int bnIdx[2][4] = {{1,2,3,4},{9,10,11,12}};
  const int wIdx[2]  = {5, 13};
  const int c1Idx[2] = {6, 14};
  const int c2Idx[2] = {7, 15};
  const int saIdx[2] = {8, 16};

  for (int L = 0; L < 2; ++L){
    const float* in  = (L == 0) ? x : (const float*)h1;
    const float* bng = (const float*)d_in[bnIdx[L][0]];
    const float* bnb = (const float*)d_in[bnIdx[L][1]];
    const float* bnm = (const float*)d_in[bnIdx[L][2]];
    const float* bnv = (const float*)d_in[bnIdx[L][3]];
    const float* wcv = (const float*)d_in[wIdx[L]];
    const float* cw1 = (const float*)d_in[c1Idx[L]];
    const float* cw2 = (const float*)d_in[c2Idx[L]];
    const float* saw = (const float*)d_in[saIdx[L]];

    hipMemsetAsync(csum, 0, 32768, stream);  // csum + cmax (adjacent)
    k_bnrelu_tr<<<4096, 256, 0, stream>>>(in, bng, bnb, bnm, bnv, yT, csum, cmax);
    k_cmlp<<<64, 256, 0, stream>>>(csum, cmax, cw1, cw2, acb);
    k_sstats<<<512, 256, 0, stream>>>(yT, f2);
    k_saw<<<25, 256, 0, stream>>>(saw, wsp);
    k_sconv<<<128, 256, 0, stream>>>(f2, wsp, spb);
    k_cw<<<9216, 256, 0, stream>>>(wcv, wtb);
    if (L == 0)
      k_conv<0><<<1024, 256, 0, stream>>>(yT, wtb, acb, spb, nullptr, h1);
    else
      k_conv<1><<<1024, 256, 0, stream>>>(yT, wtb, acb, spb, x, (float*)d_out);
  }
}